// Round 10
// baseline (437.102 us; speedup 1.0000x reference)
//
#include <hip/hip_runtime.h>

#define LRELU(x) ((x) > 0.0f ? (x) : 0.2f * (x))

typedef short bf16x8 __attribute__((ext_vector_type(8)));
typedef short bf16x4 __attribute__((ext_vector_type(4)));
typedef float f32x4 __attribute__((ext_vector_type(4)));

__device__ __forceinline__ short f2bf(float f) {
  union { float f; unsigned u; } x{f};
  return (short)((x.u + 0x7FFF + ((x.u >> 16) & 1)) >> 16);
}

// ---------------------------------------------------------------------------
// weight repack for BOTH convs: w[s][co][ci][tap] fp32 -> wr[s][co][tap*CI+ci]
__global__ __launch_bounds__(256) void k_repack_all(
    const float* __restrict__ w1, unsigned short* __restrict__ wr1,
    const float* __restrict__ w2, unsigned short* __restrict__ wr2) {
  int idx = blockIdx.x * 256 + threadIdx.x;
  const float* w;
  unsigned short* wr;
  int CO, CI;
  if (idx < 524288) {
    w = w1; wr = wr1; CO = 128; CI = 64;
  } else {
    idx -= 524288;
    if (idx >= 2097152) return;
    w = w2; wr = wr2; CO = 256; CI = 128;
  }
  int K = CI * 16;
  int k = idx % K;
  int rest = idx / K;
  int co = rest % CO, s = rest / CO;
  int tap = k / CI, ci = k % CI;
  wr[idx] = (unsigned short)f2bf(w[((size_t)(s * CO + co) * CI + ci) * 16 + tap]);
}

// ---------------------------------------------------------------------------
// conv0: img (B,1,128,128) -> x0t NHWC bf16 (B,64*64,64), k4 s2 p1, bias+leaky
__global__ __launch_bounds__(256) void k_conv0(
    const float* __restrict__ img, const float* __restrict__ w0,
    const float* __restrict__ b0, const int* __restrict__ sidx,
    unsigned short* __restrict__ x0t) {
  __shared__ float Ish[4 * 34];
  const int t = threadIdx.x;
  const int b = blockIdx.x;
  const int py = blockIdx.y;
  const int oh = py >> 2, owb = (py & 3) << 4;
  const int s = sidx[b];
  const float* ip = img + (size_t)b * 16384;
  if (t < 136) {
    int r = t / 34, c = t % 34;
    int ih = 2 * oh - 1 + r, iw = 2 * owb - 1 + c;
    Ish[t] = ((unsigned)ih < 128u && (unsigned)iw < 128u) ? ip[ih * 128 + iw] : 0.f;
  }
  const int co = t & 63, ps = t >> 6;
  float wr[16];
  const float* wp = w0 + (s * 64 + co) * 16;
#pragma unroll
  for (int i = 0; i < 16; i++) wr[i] = wp[i];
  float bb = b0[s * 64 + co];
  __syncthreads();
  unsigned short* op = x0t + ((size_t)b * 4096 + oh * 64 + owb) * 64 + co;
#pragma unroll
  for (int j = 0; j < 4; j++) {
    int pl = ps * 4 + j;
    float acc = bb;
#pragma unroll
    for (int kh = 0; kh < 4; kh++)
#pragma unroll
      for (int kw = 0; kw < 4; kw++)
        acc += wr[kh * 4 + kw] * Ish[kh * 34 + pl * 2 + kw];
    acc = LRELU(acc);
    op[pl * 64] = (unsigned short)f2bf(acc);
  }
}

// ---------------------------------------------------------------------------
// conv1: barrier-free MFMA implicit GEMM (64ci->128co, 64x64 in), fp32 NCHW out
__global__ __launch_bounds__(256) void k_conv1(
    const unsigned short* __restrict__ xt, const unsigned short* __restrict__ wr,
    const int* __restrict__ sidx, float* __restrict__ out) {
  constexpr int CI = 64, CO = 128, HIN = 64, WIN = 64, OW = 32;
  constexpr int NPB = 1024, NT = 16, CPT = 2;
  const int t = threadIdx.x;
  const int b = blockIdx.x;
  const int co0 = (blockIdx.y / NT) * 64;
  const int n0 = (blockIdx.y % NT) * 64;
  const int s = sidx[b];
  const int lane = t & 63, wv = t >> 6;
  const int wm = (wv >> 1) * 32, wn = (wv & 1) * 32;
  const int quad = lane >> 4, l16 = lane & 15;

  const unsigned short* aptr0 = wr + (size_t)(s * CO + co0 + wm + l16) * (CI * 16) + quad * 8;
  const unsigned short* aptr1 = aptr0 + (size_t)16 * (CI * 16);
  const unsigned short* xb = xt + (size_t)b * (HIN * WIN) * CI;
  int ihb[2], iwb[2];
#pragma unroll
  for (int j = 0; j < 2; j++) {
    int p = n0 + wn + j * 16 + l16;
    int oh = p >> 5, ow = p & (OW - 1);
    ihb[j] = 2 * oh - 1;
    iwb[j] = 2 * ow - 1;
  }
  f32x4 acc[2][2];
#pragma unroll
  for (int i = 0; i < 2; i++)
#pragma unroll
    for (int j = 0; j < 2; j++) acc[i][j] = (f32x4){0.f, 0.f, 0.f, 0.f};

#pragma unroll 4
  for (int kc = 0; kc < 32; kc++) {
    int tap = kc / CPT;
    int cio = (kc % CPT) * 32 + quad * 8;
    int kh = tap >> 2, kw = tap & 3;
    bf16x8 af0 = *(const bf16x8*)(aptr0 + kc * 32);
    bf16x8 af1 = *(const bf16x8*)(aptr1 + kc * 32);
    bf16x8 bfv[2];
#pragma unroll
    for (int j = 0; j < 2; j++) {
      int ih = ihb[j] + kh, iw = iwb[j] + kw;
      bf16x8 bv = {0, 0, 0, 0, 0, 0, 0, 0};
      if ((unsigned)ih < (unsigned)HIN && (unsigned)iw < (unsigned)WIN)
        bv = *(const bf16x8*)(xb + ((size_t)(ih * WIN + iw)) * CI + cio);
      bfv[j] = bv;
    }
#pragma unroll
    for (int j = 0; j < 2; j++) {
      acc[0][j] = __builtin_amdgcn_mfma_f32_16x16x32_bf16(af0, bfv[j], acc[0][j], 0, 0, 0);
      acc[1][j] = __builtin_amdgcn_mfma_f32_16x16x32_bf16(af1, bfv[j], acc[1][j], 0, 0, 0);
    }
  }
#pragma unroll
  for (int i = 0; i < 2; i++) {
    int cobase = co0 + wm + i * 16 + quad * 4;
#pragma unroll
    for (int j = 0; j < 2; j++) {
      int n = n0 + wn + j * 16 + l16;
#pragma unroll
      for (int r = 0; r < 4; r++)
        out[((size_t)b * CO + cobase + r) * NPB + n] = acc[i][j][r];
    }
  }
}

// ---------------------------------------------------------------------------
// in-place instance norm (+leaky), NPIX per (b,c)
template <int NPIX>
__global__ __launch_bounds__(256) void k_inorm(float* __restrict__ x) {
  constexpr int E = NPIX / 256;
  float* p = x + (size_t)blockIdx.x * NPIX;
  const int t = threadIdx.x;
  float v[E];
  float sum = 0.f, sq = 0.f;
#pragma unroll
  for (int i = 0; i < E; i++) {
    v[i] = p[i * 256 + t];
    sum += v[i];
    sq += v[i] * v[i];
  }
#pragma unroll
  for (int o = 32; o > 0; o >>= 1) {
    sum += __shfl_down(sum, o, 64);
    sq += __shfl_down(sq, o, 64);
  }
  __shared__ float red[8];
  int wid = t >> 6;
  if ((t & 63) == 0) {
    red[wid] = sum;
    red[4 + wid] = sq;
  }
  __syncthreads();
  float S = red[0] + red[1] + red[2] + red[3];
  float SQ = red[4] + red[5] + red[6] + red[7];
  float m = S * (1.0f / NPIX);
  float var = SQ * (1.0f / NPIX) - m * m;
  float inv = rsqrtf(var + 1e-5f);
#pragma unroll
  for (int i = 0; i < E; i++) p[i * 256 + t] = LRELU((v[i] - m) * inv);
}

// ---------------------------------------------------------------------------
// fused q/k/v 1x1 projections. grid (B, 40): y<4 q, y<8 k, else v (chunked bf16)
__global__ __launch_bounds__(256) void k_proj_qkv(
    const float* __restrict__ xin, const float* __restrict__ wq,
    const float* __restrict__ bq, const float* __restrict__ wk,
    const float* __restrict__ bk, const float* __restrict__ wv,
    const float* __restrict__ bv, const int* __restrict__ sidx,
    float* __restrict__ q, float* __restrict__ kout, unsigned short* __restrict__ vpk) {
  __shared__ float xsh[32 * 256];
  __shared__ float wsh[16 * 32];
  const int t = threadIdx.x;
  const int b = blockIdx.x;
  const int y = blockIdx.y;
  const int s = sidx[b];
  const int cg = t >> 6, ng = t & 63;
  const float* w;
  const float* bias;
  int co0, nn0, CO;
  if (y < 8) {
    w = (y < 4) ? wq : wk;
    bias = (y < 4) ? bq : bk;
    co0 = 0;
    nn0 = (y & 3) * 256;
    CO = 16;
  } else {
    w = wv;
    bias = bv;
    co0 = ((y - 8) >> 2) * 16;
    nn0 = ((y - 8) & 3) * 256;
    CO = 128;
  }
  const float* xb = xin + (size_t)b * 128 * 1024;
  float4 acc4[4];
#pragma unroll
  for (int c = 0; c < 4; c++) {
    float bb = bias[s * CO + co0 + cg * 4 + c];
    acc4[c] = make_float4(bb, bb, bb, bb);
  }
  for (int cc = 0; cc < 4; cc++) {
#pragma unroll
    for (int k = 0; k < 8; k++) {
      int id = t + (k << 8);
      int ci = id >> 6, nf = id & 63;
      ((float4*)xsh)[id] = ((const float4*)(xb + (cc * 32 + ci) * 1024 + nn0))[nf];
    }
    if (t < 128)
      ((float4*)wsh)[t] =
          ((const float4*)(w + ((size_t)(s * CO + co0 + (t >> 3))) * 128 + cc * 32))[t & 7];
    __syncthreads();
#pragma unroll
    for (int ci4 = 0; ci4 < 8; ci4++) {
      float4 wvv[4], xv[4];
#pragma unroll
      for (int c = 0; c < 4; c++) wvv[c] = ((const float4*)wsh)[(cg * 4 + c) * 8 + ci4];
#pragma unroll
      for (int i = 0; i < 4; i++) xv[i] = ((const float4*)xsh)[(ci4 * 4 + i) * 64 + ng];
#pragma unroll
      for (int c = 0; c < 4; c++)
#pragma unroll
        for (int i = 0; i < 4; i++) {
          float wvc = i == 0 ? wvv[c].x : i == 1 ? wvv[c].y : i == 2 ? wvv[c].z : wvv[c].w;
          acc4[c].x += wvc * xv[i].x;
          acc4[c].y += wvc * xv[i].y;
          acc4[c].z += wvc * xv[i].z;
          acc4[c].w += wvc * xv[i].w;
        }
    }
    __syncthreads();
  }
  if (y < 8) {
    float* out = (y < 4) ? q : kout;
#pragma unroll
    for (int c = 0; c < 4; c++)
      ((float4*)(out + ((size_t)b * 16 + cg * 4 + c) * 1024 + nn0))[ng] = acc4[c];
  } else {
    int n = nn0 + ng * 4;
#pragma unroll
    for (int c = 0; c < 4; c++) {
      int co = co0 + cg * 4 + c;
      bf16x4 u;
      u[0] = f2bf(acc4[c].x);
      u[1] = f2bf(acc4[c].y);
      u[2] = f2bf(acc4[c].z);
      u[3] = f2bf(acc4[c].w);
      *(bf16x4*)(vpk + (((size_t)b * 32 + (n >> 5)) * 128 + co) * 32 + (n & 31)) = u;
    }
  }
}

// ---------------------------------------------------------------------------
// fused self-attention (unchanged from round 9)
__global__ __launch_bounds__(256) void k_attn(
    const float* __restrict__ q, const float* __restrict__ k,
    const unsigned short* __restrict__ vpk, const float* __restrict__ x1,
    const float* __restrict__ gamma, const int* __restrict__ sidx,
    unsigned short* __restrict__ ybf) {
  __shared__ __align__(16) short Psh[16 * 1032];
  __shared__ float qsh[256];
  __shared__ float redm[64], reds[64];
  const int t = threadIdx.x;
  const int b = blockIdx.x >> 6;
  const int n0 = (blockIdx.x & 63) << 4;
  const int lane = t & 63, wv = t >> 6;
  const int quad = lane >> 4, l16 = lane & 15;
  const float* qb = q + (size_t)b * 16 * 1024;
  const float* kb = k + (size_t)b * 16 * 1024;
  const float* xb = x1 + (size_t)b * 128 * 1024;

  qsh[t] = qb[((t >> 4) << 10) + n0 + (t & 15)];
  __syncthreads();

  float acc[4][16];
#pragma unroll
  for (int j = 0; j < 4; j++)
#pragma unroll
    for (int nl = 0; nl < 16; nl++) acc[j][nl] = 0.0f;
#pragma unroll
  for (int c = 0; c < 16; c++) {
    float4 kv = *(const float4*)(kb + (c << 10) + 4 * t);
    const float* qr = qsh + c * 16;
#pragma unroll
    for (int j = 0; j < 4; j++) {
      float kk = j == 0 ? kv.x : j == 1 ? kv.y : j == 2 ? kv.z : kv.w;
#pragma unroll
      for (int nl = 0; nl < 16; nl++) acc[j][nl] += kk * qr[nl];
    }
  }
  float lmax[16];
#pragma unroll
  for (int nl = 0; nl < 16; nl++)
    lmax[nl] = fmaxf(fmaxf(acc[0][nl], acc[1][nl]), fmaxf(acc[2][nl], acc[3][nl]));
#pragma unroll
  for (int o = 32; o > 0; o >>= 1)
#pragma unroll
    for (int nl = 0; nl < 16; nl++) lmax[nl] = fmaxf(lmax[nl], __shfl_xor(lmax[nl], o, 64));
  if (lane == 0)
#pragma unroll
    for (int nl = 0; nl < 16; nl++) redm[wv * 16 + nl] = lmax[nl];
  __syncthreads();
#pragma unroll
  for (int nl = 0; nl < 16; nl++)
    lmax[nl] = fmaxf(fmaxf(redm[nl], redm[16 + nl]), fmaxf(redm[32 + nl], redm[48 + nl]));
  float lsum[16];
#pragma unroll
  for (int nl = 0; nl < 16; nl++) lsum[nl] = 0.0f;
#pragma unroll
  for (int j = 0; j < 4; j++)
#pragma unroll
    for (int nl = 0; nl < 16; nl++) {
      float e = __expf(acc[j][nl] - lmax[nl]);
      acc[j][nl] = e;
      lsum[nl] += e;
    }
#pragma unroll
  for (int o = 32; o > 0; o >>= 1)
#pragma unroll
    for (int nl = 0; nl < 16; nl++) lsum[nl] += __shfl_xor(lsum[nl], o, 64);
  if (lane == 0)
#pragma unroll
    for (int nl = 0; nl < 16; nl++) reds[wv * 16 + nl] = lsum[nl];
#pragma unroll
  for (int nl = 0; nl < 16; nl++) {
    bf16x4 pv;
    pv[0] = f2bf(acc[0][nl]);
    pv[1] = f2bf(acc[1][nl]);
    pv[2] = f2bf(acc[2][nl]);
    pv[3] = f2bf(acc[3][nl]);
    *(bf16x4*)&Psh[nl * 1032 + 4 * t] = pv;
  }
  __syncthreads();

  const unsigned short* vp =
      vpk + ((size_t)b * 32 * 128 + (size_t)(wv * 32 + l16)) * 32 + quad * 8;
  const short* prow = Psh + l16 * 1032 + quad * 8;
  f32x4 dacc[2];
  dacc[0] = (f32x4){0.f, 0.f, 0.f, 0.f};
  dacc[1] = (f32x4){0.f, 0.f, 0.f, 0.f};
#pragma unroll 8
  for (int mt = 0; mt < 32; mt++) {
    bf16x8 af0 = *(const bf16x8*)(vp + mt * 4096);
    bf16x8 af1 = *(const bf16x8*)(vp + 512 + mt * 4096);
    bf16x8 bfr = *(const bf16x8*)(prow + mt * 32);
    dacc[0] = __builtin_amdgcn_mfma_f32_16x16x32_bf16(af0, bfr, dacc[0], 0, 0, 0);
    dacc[1] = __builtin_amdgcn_mfma_f32_16x16x32_bf16(af1, bfr, dacc[1], 0, 0, 0);
  }
  __syncthreads();

  float* Osh = (float*)Psh;
  short* Osh2 = Psh + 4352;
#pragma unroll
  for (int i = 0; i < 2; i++) {
    int cob = wv * 32 + i * 16 + quad * 4;
#pragma unroll
    for (int r = 0; r < 4; r++) Osh[(cob + r) * 17 + l16] = dacc[i][r];
  }
  __syncthreads();
  float g = gamma[sidx[b]];
  {
    int co = t >> 1, j0 = (t & 1) * 8;
    const float* xr = xb + (co << 10) + n0 + j0;
    float4 xv0 = *(const float4*)xr;
    float4 xv1 = *(const float4*)(xr + 4);
    float xs[8] = {xv0.x, xv0.y, xv0.z, xv0.w, xv1.x, xv1.y, xv1.z, xv1.w};
#pragma unroll
    for (int j = 0; j < 8; j++) {
      int nl = j0 + j;
      float rs = 1.0f / (reds[nl] + reds[16 + nl] + reds[32 + nl] + reds[48 + nl]);
      Osh2[nl * 136 + co] = f2bf(g * Osh[co * 17 + nl] * rs + xs[j]);
    }
  }
  __syncthreads();
  {
    int nl = t >> 4, cg = t & 15;
    bf16x8 u = *(const bf16x8*)&Osh2[nl * 136 + cg * 8];
    *(bf16x8*)(ybf + ((size_t)b * 1024 + n0 + nl) * 128 + cg * 8) = u;
  }
}

// ---------------------------------------------------------------------------
// conv2 + sum + instance-norm fused. grid (B,4): co-tile 64, full n=256.
// Waves 2x2: wm=(wv>>1)*32 co, wn=(wv&1)*128 n. acc[2][8]. Barrier-free K-loop.
__global__ __launch_bounds__(256) void k_conv2f(
    const unsigned short* __restrict__ ybf, const unsigned short* __restrict__ wr,
    const int* __restrict__ sidx, float* __restrict__ x2) {
  constexpr int CI = 128, CO = 256;
  const int t = threadIdx.x;
  const int b = blockIdx.x;
  const int co0 = blockIdx.y * 64;
  const int s = sidx[b];
  const int lane = t & 63, wv = t >> 6;
  const int wm = (wv >> 1) * 32, wn = (wv & 1) * 128;
  const int quad = lane >> 4, l16 = lane & 15;

  const unsigned short* aptr0 = wr + (size_t)(s * CO + co0 + wm + l16) * (CI * 16) + quad * 8;
  const unsigned short* aptr1 = aptr0 + (size_t)16 * (CI * 16);
  const unsigned short* xb = ybf + (size_t)b * 1024 * CI;
  int ihb[8], iwb[8];
#pragma unroll
  for (int j = 0; j < 8; j++) {
    int p = wn + j * 16 + l16;
    int oh = p >> 4, ow = p & 15;
    ihb[j] = 2 * oh - 1;
    iwb[j] = 2 * ow - 1;
  }
  f32x4 acc[2][8];
#pragma unroll
  for (int i = 0; i < 2; i++)
#pragma unroll
    for (int j = 0; j < 8; j++) acc[i][j] = (f32x4){0.f, 0.f, 0.f, 0.f};

#pragma unroll 2
  for (int kc = 0; kc < 64; kc++) {
    int tap = kc >> 2;
    int cio = (kc & 3) * 32 + quad * 8;
    int kh = tap >> 2, kw = tap & 3;
    bf16x8 af0 = *(const bf16x8*)(aptr0 + kc * 32);
    bf16x8 af1 = *(const bf16x8*)(aptr1 + kc * 32);
#pragma unroll
    for (int j = 0; j < 8; j++) {
      int ih = ihb[j] + kh, iw = iwb[j] + kw;
      bf16x8 bv = {0, 0, 0, 0, 0, 0, 0, 0};
      if ((unsigned)ih < 32u && (unsigned)iw < 32u)
        bv = *(const bf16x8*)(xb + ((size_t)(ih * 32 + iw)) * CI + cio);
      acc[0][j] = __builtin_amdgcn_mfma_f32_16x16x32_bf16(af0, bv, acc[0][j], 0, 0, 0);
      acc[1][j] = __builtin_amdgcn_mfma_f32_16x16x32_bf16(af1, bv, acc[1][j], 0, 0, 0);
    }
  }
  // ---- fused instance norm over n=256 per co
  __shared__ float rsum[2][64], rsq[2][64];
  float psum[2][4], psq[2][4];
#pragma unroll
  for (int i = 0; i < 2; i++)
#pragma unroll
    for (int r = 0; r < 4; r++) {
      float sv = 0.f, qv = 0.f;
#pragma unroll
      for (int j = 0; j < 8; j++) {
        float v = acc[i][j][r];
        sv += v;
        qv += v * v;
      }
#pragma unroll
      for (int o = 8; o > 0; o >>= 1) {
        sv += __shfl_xor(sv, o, 64);
        qv += __shfl_xor(qv, o, 64);
      }
      psum[i][r] = sv;
      psq[i][r] = qv;
    }
  if (l16 == 0) {
    int half = wv & 1;
#pragma unroll
    for (int i = 0; i < 2; i++)
#pragma unroll
      for (int r = 0; r < 4; r++) {
        int cof = wm + i * 16 + quad * 4 + r;
        rsum[half][cof] = psum[i][r];
        rsq[half][cof] = psq[i][r];
      }
  }
  __syncthreads();
#pragma unroll
  for (int i = 0; i < 2; i++) {
    int cofb = wm + i * 16 + quad * 4;
#pragma unroll
    for (int r = 0; r < 4; r++) {
      int cof = cofb + r;
      float S = rsum[0][cof] + rsum[1][cof];
      float SQ = rsq[0][cof] + rsq[1][cof];
      float m = S * (1.0f / 256.0f);
      float var = SQ * (1.0f / 256.0f) - m * m;
      float inv = rsqrtf(var + 1e-5f);
      float* orow = x2 + ((size_t)b * CO + co0 + cof) * 256;
#pragma unroll
      for (int j = 0; j < 8; j++) {
        float v = (acc[i][j][r] - m) * inv;
        orow[wn + j * 16 + l16] = LRELU(v);
      }
    }
  }
}

// ---------------------------------------------------------------------------
// head: single kernel, grid (B). 8 chunks of 32 ci staged in LDS.
__global__ __launch_bounds__(256) void k_head(
    const float* __restrict__ x2, const float* __restrict__ wh,
    const float* __restrict__ bh, const int* __restrict__ sidx,
    float* __restrict__ out) {
  __shared__ float Xs[32 * 256];
  __shared__ float Wsh[512];
  const int t = threadIdx.x;
  const int b = blockIdx.x;
  const int s = sidx[b];
  float acc = 0.0f;
  int oh = t / 15, ow = t % 15;
  for (int cc = 0; cc < 8; cc++) {
    __syncthreads();
    const float* xp = x2 + ((size_t)b * 256 + cc * 32) * 256;
#pragma unroll
    for (int i = 0; i < 32; i++) Xs[i * 256 + t] = xp[i * 256 + t];
#pragma unroll
    for (int i = 0; i < 2; i++) {
      int idx = i * 256 + t;
      Wsh[idx] = wh[s * 4096 + cc * 512 + idx];
    }
    __syncthreads();
    if (t < 225) {
      for (int ci = 0; ci < 32; ci++) {
        const float* xr = Xs + ci * 256;
        const float* wr = Wsh + ci * 16;
#pragma unroll
        for (int kh = 0; kh < 4; kh++) {
          int ih = oh - 1 + kh;
          if ((unsigned)ih >= 16u) continue;
#pragma unroll
          for (int kw = 0; kw < 4; kw++) {
            int iw = ow - 1 + kw;
            if ((unsigned)iw >= 16u) continue;
            acc += wr[kh * 4 + kw] * xr[(ih << 4) + iw];
          }
        }
      }
    }
  }
  if (t < 225) out[b * 225 + t] = acc + bh[s];
}

// ---------------------------------------------------------------------------
extern "C" void kernel_launch(void* const* d_in, const int* in_sizes, int n_in,
                              void* d_out, int out_size, void* d_ws, size_t ws_size,
                              hipStream_t stream) {
  const float* img = (const float*)d_in[0];
  const int* sidx = (const int*)d_in[1];
  const float* w0 = (const float*)d_in[2];
  const float* b0 = (const float*)d_in[3];
  const float* w1 = (const float*)d_in[4];
  const float* w2 = (const float*)d_in[6];
  const float* wq = (const float*)d_in[8];
  const float* bq = (const float*)d_in[9];
  const float* wk = (const float*)d_in[10];
  const float* bk = (const float*)d_in[11];
  const float* wv = (const float*)d_in[12];
  const float* bv = (const float*)d_in[13];
  const float* gamma = (const float*)d_in[14];
  const float* wh = (const float*)d_in[15];
  const float* bh = (const float*)d_in[16];
  float* out = (float*)d_out;

  float* ws = (float*)d_ws;
  unsigned short* x0t = (unsigned short*)(ws);            // [0,2M) floats span
  float* x1 = ws + 2097152;                               // [2M,4M)
  float* q = ws + 4194304;                                // [4M,4.25M)
  float* k = ws + 4456448;                                // [4.25M,4.5M)
  unsigned short* vpk = (unsigned short*)(ws + 4718592);  // [4.5M,5.5M)
  unsigned short* ybf = (unsigned short*)(ws + 5767168);  // [5.5M,6.5M)
  float* x2 = ws + 6815744;                               // [6.5M,7.5M)
  unsigned short* wr1 = (unsigned short*)(ws + 8388608);  // [8M,8.25M)
  unsigned short* wr2 = (unsigned short*)(ws + 8650752);  // [8.25M,9.25M)

  const int B = 16;

  k_repack_all<<<10240, 256, 0, stream>>>(w1, wr1, w2, wr2);
  k_conv0<<<dim3(B, 256), 256, 0, stream>>>(img, w0, b0, sidx, x0t);
  k_conv1<<<dim3(B, 32), 256, 0, stream>>>(x0t, wr1, sidx, x1);
  k_inorm<1024><<<B * 128, 256, 0, stream>>>(x1);
  k_proj_qkv<<<dim3(B, 40), 256, 0, stream>>>(x1, wq, bq, wk, bk, wv, bv, sidx, q, k, vpk);
  k_attn<<<B * 64, 256, 0, stream>>>(q, k, vpk, x1, gamma, sidx, ybf);
  k_conv2f<<<dim3(B, 4), 256, 0, stream>>>(ybf, wr2, sidx, x2);
  k_head<<<B, 256, 0, stream>>>(x2, wh, bh, sidx, out);
}

// Round 11
// 272.117 us; speedup vs baseline: 1.6063x; 1.6063x over previous
//
#include <hip/hip_runtime.h>

#define LRELU(x) ((x) > 0.0f ? (x) : 0.2f * (x))

typedef short bf16x8 __attribute__((ext_vector_type(8)));
typedef short bf16x4 __attribute__((ext_vector_type(4)));
typedef float f32x4 __attribute__((ext_vector_type(4)));

__device__ __forceinline__ short f2bf(float f) {
  union { float f; unsigned u; } x{f};
  return (short)((x.u + 0x7FFF + ((x.u >> 16) & 1)) >> 16);
}

// ---------------------------------------------------------------------------
// weight repack for BOTH convs: w[s][co][ci][tap] fp32 -> wr[s][co][tap*CI+ci]
__global__ __launch_bounds__(256) void k_repack_all(
    const float* __restrict__ w1, unsigned short* __restrict__ wr1,
    const float* __restrict__ w2, unsigned short* __restrict__ wr2) {
  int idx = blockIdx.x * 256 + threadIdx.x;
  const float* w;
  unsigned short* wr;
  int CO, CI;
  if (idx < 524288) {
    w = w1; wr = wr1; CO = 128; CI = 64;
  } else {
    idx -= 524288;
    if (idx >= 2097152) return;
    w = w2; wr = wr2; CO = 256; CI = 128;
  }
  int K = CI * 16;
  int k = idx % K;
  int rest = idx / K;
  int co = rest % CO, s = rest / CO;
  int tap = k / CI, ci = k % CI;
  wr[idx] = (unsigned short)f2bf(w[((size_t)(s * CO + co) * CI + ci) * 16 + tap]);
}

// ---------------------------------------------------------------------------
// conv0: img (B,1,128,128) -> x0t NHWC bf16 (B,64*64,64), k4 s2 p1, bias+leaky
__global__ __launch_bounds__(256) void k_conv0(
    const float* __restrict__ img, const float* __restrict__ w0,
    const float* __restrict__ b0, const int* __restrict__ sidx,
    unsigned short* __restrict__ x0t) {
  __shared__ float Ish[4 * 34];
  const int t = threadIdx.x;
  const int b = blockIdx.x;
  const int py = blockIdx.y;
  const int oh = py >> 2, owb = (py & 3) << 4;
  const int s = sidx[b];
  const float* ip = img + (size_t)b * 16384;
  if (t < 136) {
    int r = t / 34, c = t % 34;
    int ih = 2 * oh - 1 + r, iw = 2 * owb - 1 + c;
    Ish[t] = ((unsigned)ih < 128u && (unsigned)iw < 128u) ? ip[ih * 128 + iw] : 0.f;
  }
  const int co = t & 63, ps = t >> 6;
  float wr[16];
  const float* wp = w0 + (s * 64 + co) * 16;
#pragma unroll
  for (int i = 0; i < 16; i++) wr[i] = wp[i];
  float bb = b0[s * 64 + co];
  __syncthreads();
  unsigned short* op = x0t + ((size_t)b * 4096 + oh * 64 + owb) * 64 + co;
#pragma unroll
  for (int j = 0; j < 4; j++) {
    int pl = ps * 4 + j;
    float acc = bb;
#pragma unroll
    for (int kh = 0; kh < 4; kh++)
#pragma unroll
      for (int kw = 0; kw < 4; kw++)
        acc += wr[kh * 4 + kw] * Ish[kh * 34 + pl * 2 + kw];
    acc = LRELU(acc);
    op[pl * 64] = (unsigned short)f2bf(acc);
  }
}

// ---------------------------------------------------------------------------
// conv1: barrier-free MFMA implicit GEMM (64ci->128co, 64x64 in), fp32 NCHW out
__global__ __launch_bounds__(256) void k_conv1(
    const unsigned short* __restrict__ xt, const unsigned short* __restrict__ wr,
    const int* __restrict__ sidx, float* __restrict__ out) {
  constexpr int CI = 64, CO = 128, HIN = 64, WIN = 64, OW = 32;
  constexpr int NPB = 1024, NT = 16, CPT = 2;
  const int t = threadIdx.x;
  const int b = blockIdx.x;
  const int co0 = (blockIdx.y / NT) * 64;
  const int n0 = (blockIdx.y % NT) * 64;
  const int s = sidx[b];
  const int lane = t & 63, wv = t >> 6;
  const int wm = (wv >> 1) * 32, wn = (wv & 1) * 32;
  const int quad = lane >> 4, l16 = lane & 15;

  const unsigned short* aptr0 = wr + (size_t)(s * CO + co0 + wm + l16) * (CI * 16) + quad * 8;
  const unsigned short* aptr1 = aptr0 + (size_t)16 * (CI * 16);
  const unsigned short* xb = xt + (size_t)b * (HIN * WIN) * CI;
  int ihb[2], iwb[2];
#pragma unroll
  for (int j = 0; j < 2; j++) {
    int p = n0 + wn + j * 16 + l16;
    int oh = p >> 5, ow = p & (OW - 1);
    ihb[j] = 2 * oh - 1;
    iwb[j] = 2 * ow - 1;
  }
  f32x4 acc[2][2];
#pragma unroll
  for (int i = 0; i < 2; i++)
#pragma unroll
    for (int j = 0; j < 2; j++) acc[i][j] = (f32x4){0.f, 0.f, 0.f, 0.f};

#pragma unroll 4
  for (int kc = 0; kc < 32; kc++) {
    int tap = kc / CPT;
    int cio = (kc % CPT) * 32 + quad * 8;
    int kh = tap >> 2, kw = tap & 3;
    bf16x8 af0 = *(const bf16x8*)(aptr0 + kc * 32);
    bf16x8 af1 = *(const bf16x8*)(aptr1 + kc * 32);
    bf16x8 bfv[2];
#pragma unroll
    for (int j = 0; j < 2; j++) {
      int ih = ihb[j] + kh, iw = iwb[j] + kw;
      bf16x8 bv = {0, 0, 0, 0, 0, 0, 0, 0};
      if ((unsigned)ih < (unsigned)HIN && (unsigned)iw < (unsigned)WIN)
        bv = *(const bf16x8*)(xb + ((size_t)(ih * WIN + iw)) * CI + cio);
      bfv[j] = bv;
    }
#pragma unroll
    for (int j = 0; j < 2; j++) {
      acc[0][j] = __builtin_amdgcn_mfma_f32_16x16x32_bf16(af0, bfv[j], acc[0][j], 0, 0, 0);
      acc[1][j] = __builtin_amdgcn_mfma_f32_16x16x32_bf16(af1, bfv[j], acc[1][j], 0, 0, 0);
    }
  }
#pragma unroll
  for (int i = 0; i < 2; i++) {
    int cobase = co0 + wm + i * 16 + quad * 4;
#pragma unroll
    for (int j = 0; j < 2; j++) {
      int n = n0 + wn + j * 16 + l16;
#pragma unroll
      for (int r = 0; r < 4; r++)
        out[((size_t)b * CO + cobase + r) * NPB + n] = acc[i][j][r];
    }
  }
}

// ---------------------------------------------------------------------------
// in-place instance norm (+leaky), NPIX per (b,c)
template <int NPIX>
__global__ __launch_bounds__(256) void k_inorm(float* __restrict__ x) {
  constexpr int E = NPIX / 256;
  float* p = x + (size_t)blockIdx.x * NPIX;
  const int t = threadIdx.x;
  float v[E];
  float sum = 0.f, sq = 0.f;
#pragma unroll
  for (int i = 0; i < E; i++) {
    v[i] = p[i * 256 + t];
    sum += v[i];
    sq += v[i] * v[i];
  }
#pragma unroll
  for (int o = 32; o > 0; o >>= 1) {
    sum += __shfl_down(sum, o, 64);
    sq += __shfl_down(sq, o, 64);
  }
  __shared__ float red[8];
  int wid = t >> 6;
  if ((t & 63) == 0) {
    red[wid] = sum;
    red[4 + wid] = sq;
  }
  __syncthreads();
  float S = red[0] + red[1] + red[2] + red[3];
  float SQ = red[4] + red[5] + red[6] + red[7];
  float m = S * (1.0f / NPIX);
  float var = SQ * (1.0f / NPIX) - m * m;
  float inv = rsqrtf(var + 1e-5f);
#pragma unroll
  for (int i = 0; i < E; i++) p[i * 256 + t] = LRELU((v[i] - m) * inv);
}

// ---------------------------------------------------------------------------
// fused q/k/v 1x1 projections. grid (B, 40): y<4 q, y<8 k, else v (chunked bf16)
__global__ __launch_bounds__(256) void k_proj_qkv(
    const float* __restrict__ xin, const float* __restrict__ wq,
    const float* __restrict__ bq, const float* __restrict__ wk,
    const float* __restrict__ bk, const float* __restrict__ wv,
    const float* __restrict__ bv, const int* __restrict__ sidx,
    float* __restrict__ q, float* __restrict__ kout, unsigned short* __restrict__ vpk) {
  __shared__ float xsh[32 * 256];
  __shared__ float wsh[16 * 32];
  const int t = threadIdx.x;
  const int b = blockIdx.x;
  const int y = blockIdx.y;
  const int s = sidx[b];
  const int cg = t >> 6, ng = t & 63;
  const float* w;
  const float* bias;
  int co0, nn0, CO;
  if (y < 8) {
    w = (y < 4) ? wq : wk;
    bias = (y < 4) ? bq : bk;
    co0 = 0;
    nn0 = (y & 3) * 256;
    CO = 16;
  } else {
    w = wv;
    bias = bv;
    co0 = ((y - 8) >> 2) * 16;
    nn0 = ((y - 8) & 3) * 256;
    CO = 128;
  }
  const float* xb = xin + (size_t)b * 128 * 1024;
  float4 acc4[4];
#pragma unroll
  for (int c = 0; c < 4; c++) {
    float bb = bias[s * CO + co0 + cg * 4 + c];
    acc4[c] = make_float4(bb, bb, bb, bb);
  }
  for (int cc = 0; cc < 4; cc++) {
#pragma unroll
    for (int k = 0; k < 8; k++) {
      int id = t + (k << 8);
      int ci = id >> 6, nf = id & 63;
      ((float4*)xsh)[id] = ((const float4*)(xb + (cc * 32 + ci) * 1024 + nn0))[nf];
    }
    if (t < 128)
      ((float4*)wsh)[t] =
          ((const float4*)(w + ((size_t)(s * CO + co0 + (t >> 3))) * 128 + cc * 32))[t & 7];
    __syncthreads();
#pragma unroll
    for (int ci4 = 0; ci4 < 8; ci4++) {
      float4 wvv[4], xv[4];
#pragma unroll
      for (int c = 0; c < 4; c++) wvv[c] = ((const float4*)wsh)[(cg * 4 + c) * 8 + ci4];
#pragma unroll
      for (int i = 0; i < 4; i++) xv[i] = ((const float4*)xsh)[(ci4 * 4 + i) * 64 + ng];
#pragma unroll
      for (int c = 0; c < 4; c++)
#pragma unroll
        for (int i = 0; i < 4; i++) {
          float wvc = i == 0 ? wvv[c].x : i == 1 ? wvv[c].y : i == 2 ? wvv[c].z : wvv[c].w;
          acc4[c].x += wvc * xv[i].x;
          acc4[c].y += wvc * xv[i].y;
          acc4[c].z += wvc * xv[i].z;
          acc4[c].w += wvc * xv[i].w;
        }
    }
    __syncthreads();
  }
  if (y < 8) {
    float* out = (y < 4) ? q : kout;
#pragma unroll
    for (int c = 0; c < 4; c++)
      ((float4*)(out + ((size_t)b * 16 + cg * 4 + c) * 1024 + nn0))[ng] = acc4[c];
  } else {
    int n = nn0 + ng * 4;
#pragma unroll
    for (int c = 0; c < 4; c++) {
      int co = co0 + cg * 4 + c;
      bf16x4 u;
      u[0] = f2bf(acc4[c].x);
      u[1] = f2bf(acc4[c].y);
      u[2] = f2bf(acc4[c].z);
      u[3] = f2bf(acc4[c].w);
      *(bf16x4*)(vpk + (((size_t)b * 32 + (n >> 5)) * 128 + co) * 32 + (n & 31)) = u;
    }
  }
}

// ---------------------------------------------------------------------------
// fused self-attention (proven round-9 version)
__global__ __launch_bounds__(256) void k_attn(
    const float* __restrict__ q, const float* __restrict__ k,
    const unsigned short* __restrict__ vpk, const float* __restrict__ x1,
    const float* __restrict__ gamma, const int* __restrict__ sidx,
    unsigned short* __restrict__ ybf) {
  __shared__ __align__(16) short Psh[16 * 1032];
  __shared__ float qsh[256];
  __shared__ float redm[64], reds[64];
  const int t = threadIdx.x;
  const int b = blockIdx.x >> 6;
  const int n0 = (blockIdx.x & 63) << 4;
  const int lane = t & 63, wv = t >> 6;
  const int quad = lane >> 4, l16 = lane & 15;
  const float* qb = q + (size_t)b * 16 * 1024;
  const float* kb = k + (size_t)b * 16 * 1024;
  const float* xb = x1 + (size_t)b * 128 * 1024;

  qsh[t] = qb[((t >> 4) << 10) + n0 + (t & 15)];
  __syncthreads();

  float acc[4][16];
#pragma unroll
  for (int j = 0; j < 4; j++)
#pragma unroll
    for (int nl = 0; nl < 16; nl++) acc[j][nl] = 0.0f;
#pragma unroll
  for (int c = 0; c < 16; c++) {
    float4 kv = *(const float4*)(kb + (c << 10) + 4 * t);
    const float* qr = qsh + c * 16;
#pragma unroll
    for (int j = 0; j < 4; j++) {
      float kk = j == 0 ? kv.x : j == 1 ? kv.y : j == 2 ? kv.z : kv.w;
#pragma unroll
      for (int nl = 0; nl < 16; nl++) acc[j][nl] += kk * qr[nl];
    }
  }
  float lmax[16];
#pragma unroll
  for (int nl = 0; nl < 16; nl++)
    lmax[nl] = fmaxf(fmaxf(acc[0][nl], acc[1][nl]), fmaxf(acc[2][nl], acc[3][nl]));
#pragma unroll
  for (int o = 32; o > 0; o >>= 1)
#pragma unroll
    for (int nl = 0; nl < 16; nl++) lmax[nl] = fmaxf(lmax[nl], __shfl_xor(lmax[nl], o, 64));
  if (lane == 0)
#pragma unroll
    for (int nl = 0; nl < 16; nl++) redm[wv * 16 + nl] = lmax[nl];
  __syncthreads();
#pragma unroll
  for (int nl = 0; nl < 16; nl++)
    lmax[nl] = fmaxf(fmaxf(redm[nl], redm[16 + nl]), fmaxf(redm[32 + nl], redm[48 + nl]));
  float lsum[16];
#pragma unroll
  for (int nl = 0; nl < 16; nl++) lsum[nl] = 0.0f;
#pragma unroll
  for (int j = 0; j < 4; j++)
#pragma unroll
    for (int nl = 0; nl < 16; nl++) {
      float e = __expf(acc[j][nl] - lmax[nl]);
      acc[j][nl] = e;
      lsum[nl] += e;
    }
#pragma unroll
  for (int o = 32; o > 0; o >>= 1)
#pragma unroll
    for (int nl = 0; nl < 16; nl++) lsum[nl] += __shfl_xor(lsum[nl], o, 64);
  if (lane == 0)
#pragma unroll
    for (int nl = 0; nl < 16; nl++) reds[wv * 16 + nl] = lsum[nl];
#pragma unroll
  for (int nl = 0; nl < 16; nl++) {
    bf16x4 pv;
    pv[0] = f2bf(acc[0][nl]);
    pv[1] = f2bf(acc[1][nl]);
    pv[2] = f2bf(acc[2][nl]);
    pv[3] = f2bf(acc[3][nl]);
    *(bf16x4*)&Psh[nl * 1032 + 4 * t] = pv;
  }
  __syncthreads();

  const unsigned short* vp =
      vpk + ((size_t)b * 32 * 128 + (size_t)(wv * 32 + l16)) * 32 + quad * 8;
  const short* prow = Psh + l16 * 1032 + quad * 8;
  f32x4 dacc[2];
  dacc[0] = (f32x4){0.f, 0.f, 0.f, 0.f};
  dacc[1] = (f32x4){0.f, 0.f, 0.f, 0.f};
#pragma unroll 8
  for (int mt = 0; mt < 32; mt++) {
    bf16x8 af0 = *(const bf16x8*)(vp + mt * 4096);
    bf16x8 af1 = *(const bf16x8*)(vp + 512 + mt * 4096);
    bf16x8 bfr = *(const bf16x8*)(prow + mt * 32);
    dacc[0] = __builtin_amdgcn_mfma_f32_16x16x32_bf16(af0, bfr, dacc[0], 0, 0, 0);
    dacc[1] = __builtin_amdgcn_mfma_f32_16x16x32_bf16(af1, bfr, dacc[1], 0, 0, 0);
  }
  __syncthreads();

  float* Osh = (float*)Psh;
  short* Osh2 = Psh + 4352;
#pragma unroll
  for (int i = 0; i < 2; i++) {
    int cob = wv * 32 + i * 16 + quad * 4;
#pragma unroll
    for (int r = 0; r < 4; r++) Osh[(cob + r) * 17 + l16] = dacc[i][r];
  }
  __syncthreads();
  float g = gamma[sidx[b]];
  {
    int co = t >> 1, j0 = (t & 1) * 8;
    const float* xr = xb + (co << 10) + n0 + j0;
    float4 xv0 = *(const float4*)xr;
    float4 xv1 = *(const float4*)(xr + 4);
    float xs[8] = {xv0.x, xv0.y, xv0.z, xv0.w, xv1.x, xv1.y, xv1.z, xv1.w};
#pragma unroll
    for (int j = 0; j < 8; j++) {
      int nl = j0 + j;
      float rs = 1.0f / (reds[nl] + reds[16 + nl] + reds[32 + nl] + reds[48 + nl]);
      Osh2[nl * 136 + co] = f2bf(g * Osh[co * 17 + nl] * rs + xs[j]);
    }
  }
  __syncthreads();
  {
    int nl = t >> 4, cg = t & 15;
    bf16x8 u = *(const bf16x8*)&Osh2[nl * 136 + cg * 8];
    *(bf16x8*)(ybf + ((size_t)b * 1024 + n0 + nl) * 128 + cg * 8) = u;
  }
}

// ---------------------------------------------------------------------------
// conv2 + instance-norm fused, HIGH PARALLELISM: grid (B,16) = 256 blocks.
// Block = 16co x 256n; wave wv owns n-range [wv*64, wv*64+64). acc[4].
// Barrier-free K-loop (1 A-load + 4 B-loads + 4 MFMA per kc).
__global__ __launch_bounds__(256) void k_conv2f(
    const unsigned short* __restrict__ ybf, const unsigned short* __restrict__ wr,
    const int* __restrict__ sidx, float* __restrict__ x2) {
  constexpr int CI = 128, CO = 256;
  const int t = threadIdx.x;
  const int b = blockIdx.x;
  const int co0 = blockIdx.y * 16;
  const int s = sidx[b];
  const int lane = t & 63, wv = t >> 6;
  const int quad = lane >> 4, l16 = lane & 15;

  const unsigned short* aptr = wr + (size_t)(s * CO + co0 + l16) * (CI * 16) + quad * 8;
  const unsigned short* xb = ybf + (size_t)b * 1024 * CI;
  int ihb[4], iwb[4];
#pragma unroll
  for (int j = 0; j < 4; j++) {
    int p = wv * 64 + j * 16 + l16;
    int oh = p >> 4, ow = p & 15;
    ihb[j] = 2 * oh - 1;
    iwb[j] = 2 * ow - 1;
  }
  f32x4 acc[4];
#pragma unroll
  for (int j = 0; j < 4; j++) acc[j] = (f32x4){0.f, 0.f, 0.f, 0.f};

#pragma unroll 4
  for (int kc = 0; kc < 64; kc++) {
    int tap = kc >> 2;
    int cio = (kc & 3) * 32 + quad * 8;
    int kh = tap >> 2, kw = tap & 3;
    bf16x8 af = *(const bf16x8*)(aptr + kc * 32);
#pragma unroll
    for (int j = 0; j < 4; j++) {
      int ih = ihb[j] + kh, iw = iwb[j] + kw;
      bf16x8 bv = {0, 0, 0, 0, 0, 0, 0, 0};
      if ((unsigned)ih < 32u && (unsigned)iw < 32u)
        bv = *(const bf16x8*)(xb + ((size_t)(ih * 32 + iw)) * CI + cio);
      acc[j] = __builtin_amdgcn_mfma_f32_16x16x32_bf16(af, bv, acc[j], 0, 0, 0);
    }
  }
  // ---- fused instance norm over n=256 per co (C/D: col(n)=l16, row=quad*4+r)
  __shared__ float rsum[4][16], rsq[4][16];
#pragma unroll
  for (int r = 0; r < 4; r++) {
    float sv = 0.f, qv = 0.f;
#pragma unroll
    for (int j = 0; j < 4; j++) {
      float v = acc[j][r];
      sv += v;
      qv += v * v;
    }
#pragma unroll
    for (int o = 8; o > 0; o >>= 1) {
      sv += __shfl_xor(sv, o, 64);
      qv += __shfl_xor(qv, o, 64);
    }
    if (l16 == 0) {
      rsum[wv][quad * 4 + r] = sv;
      rsq[wv][quad * 4 + r] = qv;
    }
  }
  __syncthreads();
#pragma unroll
  for (int r = 0; r < 4; r++) {
    int cof = quad * 4 + r;
    float S = rsum[0][cof] + rsum[1][cof] + rsum[2][cof] + rsum[3][cof];
    float SQ = rsq[0][cof] + rsq[1][cof] + rsq[2][cof] + rsq[3][cof];
    float m = S * (1.0f / 256.0f);
    float var = SQ * (1.0f / 256.0f) - m * m;
    float inv = rsqrtf(var + 1e-5f);
    float* orow = x2 + ((size_t)b * CO + co0 + cof) * 256;
#pragma unroll
    for (int j = 0; j < 4; j++) {
      float v = (acc[j][r] - m) * inv;
      orow[wv * 64 + j * 16 + l16] = LRELU(v);
    }
  }
}

// ---------------------------------------------------------------------------
// head: init out with bias, then partial conv via LDS + atomicAdd (proven r8/9)
__global__ __launch_bounds__(256) void k_head_init(
    const float* __restrict__ bh, const int* __restrict__ sidx, float* __restrict__ out) {
  int i = blockIdx.x * 256 + threadIdx.x;
  if (i < 3600) out[i] = bh[sidx[i / 225]];
}

__global__ __launch_bounds__(256) void k_head_part(
    const float* __restrict__ x2, const float* __restrict__ wh,
    const int* __restrict__ sidx, float* __restrict__ out) {
  __shared__ float Xs[32 * 256];
  __shared__ float Wsh[512];
  const int t = threadIdx.x;
  const int b = blockIdx.x, cc = blockIdx.y;
  const int s = sidx[b];
  const float* xp = x2 + ((size_t)b * 256 + cc * 32) * 256;
#pragma unroll
  for (int i = 0; i < 32; i++) Xs[i * 256 + t] = xp[i * 256 + t];
#pragma unroll
  for (int i = 0; i < 2; i++) {
    int idx = i * 256 + t;
    Wsh[idx] = wh[s * 4096 + cc * 512 + idx];
  }
  __syncthreads();
  if (t < 225) {
    int oh = t / 15, ow = t % 15;
    float acc = 0.0f;
    for (int ci = 0; ci < 32; ci++) {
      const float* xr = Xs + ci * 256;
      const float* wr = Wsh + ci * 16;
#pragma unroll
      for (int kh = 0; kh < 4; kh++) {
        int ih = oh - 1 + kh;
        if ((unsigned)ih >= 16u) continue;
#pragma unroll
        for (int kw = 0; kw < 4; kw++) {
          int iw = ow - 1 + kw;
          if ((unsigned)iw >= 16u) continue;
          acc += wr[kh * 4 + kw] * xr[(ih << 4) + iw];
        }
      }
    }
    atomicAdd(out + b * 225 + t, acc);
  }
}

// ---------------------------------------------------------------------------
extern "C" void kernel_launch(void* const* d_in, const int* in_sizes, int n_in,
                              void* d_out, int out_size, void* d_ws, size_t ws_size,
                              hipStream_t stream) {
  const float* img = (const float*)d_in[0];
  const int* sidx = (const int*)d_in[1];
  const float* w0 = (const float*)d_in[2];
  const float* b0 = (const float*)d_in[3];
  const float* w1 = (const float*)d_in[4];
  const float* w2 = (const float*)d_in[6];
  const float* wq = (const float*)d_in[8];
  const float* bq = (const float*)d_in[9];
  const float* wk = (const float*)d_in[10];
  const float* bk = (const float*)d_in[11];
  const float* wv = (const float*)d_in[12];
  const float* bv = (const float*)d_in[13];
  const float* gamma = (const float*)d_in[14];
  const float* wh = (const float*)d_in[15];
  const float* bh = (const float*)d_in[16];
  float* out = (float*)d_out;

  float* ws = (float*)d_ws;
  unsigned short* x0t = (unsigned short*)(ws);            // [0,2M) floats span
  float* x1 = ws + 2097152;                               // [2M,4M)
  float* q = ws + 4194304;                                // [4M,4.25M)
  float* k = ws + 4456448;                                // [4.25M,4.5M)
  unsigned short* vpk = (unsigned short*)(ws + 4718592);  // [4.5M,5.5M)
  unsigned short* ybf = (unsigned short*)(ws + 5767168);  // [5.5M,6.5M)
  float* x2 = ws + 6815744;                               // [6.5M,7.5M)
  unsigned short* wr1 = (unsigned short*)(ws + 8388608);  // [8M,8.25M)
  unsigned short* wr2 = (unsigned short*)(ws + 8650752);  // [8.25M,9.25M)

  const int B = 16;

  k_repack_all<<<10240, 256, 0, stream>>>(w1, wr1, w2, wr2);
  k_conv0<<<dim3(B, 256), 256, 0, stream>>>(img, w0, b0, sidx, x0t);
  k_conv1<<<dim3(B, 32), 256, 0, stream>>>(x0t, wr1, sidx, x1);
  k_inorm<1024><<<B * 128, 256, 0, stream>>>(x1);
  k_proj_qkv<<<dim3(B, 40), 256, 0, stream>>>(x1, wq, bq, wk, bk, wv, bv, sidx, q, k, vpk);
  k_attn<<<B * 64, 256, 0, stream>>>(q, k, vpk, x1, gamma, sidx, ybf);
  k_conv2f<<<dim3(B, 16), 256, 0, stream>>>(ybf, wr2, sidx, x2);
  k_head_init<<<15, 256, 0, stream>>>(bh, sidx, out);
  k_head_part<<<dim3(B, 8), 256, 0, stream>>>(x2, wh, sidx, out);
}

// Round 12
// 258.482 us; speedup vs baseline: 1.6910x; 1.0528x over previous
//
#include <hip/hip_runtime.h>

#define LRELU(x) ((x) > 0.0f ? (x) : 0.2f * (x))

typedef short bf16x8 __attribute__((ext_vector_type(8)));
typedef short bf16x4 __attribute__((ext_vector_type(4)));
typedef float f32x4 __attribute__((ext_vector_type(4)));

__device__ __forceinline__ short f2bf(float f) {
  union { float f; unsigned u; } x{f};
  return (short)((x.u + 0x7FFF + ((x.u >> 16) & 1)) >> 16);
}

// ---------------------------------------------------------------------------
// weight repack for BOTH convs: w[s][co][ci][tap] fp32 -> wr[s][co][tap*CI+ci]
__global__ __launch_bounds__(256) void k_repack_all(
    const float* __restrict__ w1, unsigned short* __restrict__ wr1,
    const float* __restrict__ w2, unsigned short* __restrict__ wr2) {
  int idx = blockIdx.x * 256 + threadIdx.x;
  const float* w;
  unsigned short* wr;
  int CO, CI;
  if (idx < 524288) {
    w = w1; wr = wr1; CO = 128; CI = 64;
  } else {
    idx -= 524288;
    if (idx >= 2097152) return;
    w = w2; wr = wr2; CO = 256; CI = 128;
  }
  int K = CI * 16;
  int k = idx % K;
  int rest = idx / K;
  int co = rest % CO, s = rest / CO;
  int tap = k / CI, ci = k % CI;
  wr[idx] = (unsigned short)f2bf(w[((size_t)(s * CO + co) * CI + ci) * 16 + tap]);
}

// ---------------------------------------------------------------------------
// conv0: img (B,1,128,128) -> x0t NHWC bf16 (B,64*64,64), k4 s2 p1, bias+leaky
__global__ __launch_bounds__(256) void k_conv0(
    const float* __restrict__ img, const float* __restrict__ w0,
    const float* __restrict__ b0, const int* __restrict__ sidx,
    unsigned short* __restrict__ x0t) {
  __shared__ float Ish[4 * 34];
  const int t = threadIdx.x;
  const int b = blockIdx.x;
  const int py = blockIdx.y;
  const int oh = py >> 2, owb = (py & 3) << 4;
  const int s = sidx[b];
  const float* ip = img + (size_t)b * 16384;
  if (t < 136) {
    int r = t / 34, c = t % 34;
    int ih = 2 * oh - 1 + r, iw = 2 * owb - 1 + c;
    Ish[t] = ((unsigned)ih < 128u && (unsigned)iw < 128u) ? ip[ih * 128 + iw] : 0.f;
  }
  const int co = t & 63, ps = t >> 6;
  float wr[16];
  const float* wp = w0 + (s * 64 + co) * 16;
#pragma unroll
  for (int i = 0; i < 16; i++) wr[i] = wp[i];
  float bb = b0[s * 64 + co];
  __syncthreads();
  unsigned short* op = x0t + ((size_t)b * 4096 + oh * 64 + owb) * 64 + co;
#pragma unroll
  for (int j = 0; j < 4; j++) {
    int pl = ps * 4 + j;
    float acc = bb;
#pragma unroll
    for (int kh = 0; kh < 4; kh++)
#pragma unroll
      for (int kw = 0; kw < 4; kw++)
        acc += wr[kh * 4 + kw] * Ish[kh * 34 + pl * 2 + kw];
    acc = LRELU(acc);
    op[pl * 64] = (unsigned short)f2bf(acc);
  }
}

// ---------------------------------------------------------------------------
// conv1: barrier-free MFMA implicit GEMM (64ci->128co, 64x64 in), fp32 NCHW out
__global__ __launch_bounds__(256) void k_conv1(
    const unsigned short* __restrict__ xt, const unsigned short* __restrict__ wr,
    const int* __restrict__ sidx, float* __restrict__ out) {
  constexpr int CI = 64, CO = 128, HIN = 64, WIN = 64, OW = 32;
  constexpr int NPB = 1024, NT = 16, CPT = 2;
  const int t = threadIdx.x;
  const int b = blockIdx.x;
  const int co0 = (blockIdx.y / NT) * 64;
  const int n0 = (blockIdx.y % NT) * 64;
  const int s = sidx[b];
  const int lane = t & 63, wv = t >> 6;
  const int wm = (wv >> 1) * 32, wn = (wv & 1) * 32;
  const int quad = lane >> 4, l16 = lane & 15;

  const unsigned short* aptr0 = wr + (size_t)(s * CO + co0 + wm + l16) * (CI * 16) + quad * 8;
  const unsigned short* aptr1 = aptr0 + (size_t)16 * (CI * 16);
  const unsigned short* xb = xt + (size_t)b * (HIN * WIN) * CI;
  int ihb[2], iwb[2];
#pragma unroll
  for (int j = 0; j < 2; j++) {
    int p = n0 + wn + j * 16 + l16;
    int oh = p >> 5, ow = p & (OW - 1);
    ihb[j] = 2 * oh - 1;
    iwb[j] = 2 * ow - 1;
  }
  f32x4 acc[2][2];
#pragma unroll
  for (int i = 0; i < 2; i++)
#pragma unroll
    for (int j = 0; j < 2; j++) acc[i][j] = (f32x4){0.f, 0.f, 0.f, 0.f};

#pragma unroll 4
  for (int kc = 0; kc < 32; kc++) {
    int tap = kc / CPT;
    int cio = (kc % CPT) * 32 + quad * 8;
    int kh = tap >> 2, kw = tap & 3;
    bf16x8 af0 = *(const bf16x8*)(aptr0 + kc * 32);
    bf16x8 af1 = *(const bf16x8*)(aptr1 + kc * 32);
    bf16x8 bfv[2];
#pragma unroll
    for (int j = 0; j < 2; j++) {
      int ih = ihb[j] + kh, iw = iwb[j] + kw;
      bf16x8 bv = {0, 0, 0, 0, 0, 0, 0, 0};
      if ((unsigned)ih < (unsigned)HIN && (unsigned)iw < (unsigned)WIN)
        bv = *(const bf16x8*)(xb + ((size_t)(ih * WIN + iw)) * CI + cio);
      bfv[j] = bv;
    }
#pragma unroll
    for (int j = 0; j < 2; j++) {
      acc[0][j] = __builtin_amdgcn_mfma_f32_16x16x32_bf16(af0, bfv[j], acc[0][j], 0, 0, 0);
      acc[1][j] = __builtin_amdgcn_mfma_f32_16x16x32_bf16(af1, bfv[j], acc[1][j], 0, 0, 0);
    }
  }
#pragma unroll
  for (int i = 0; i < 2; i++) {
    int cobase = co0 + wm + i * 16 + quad * 4;
#pragma unroll
    for (int j = 0; j < 2; j++) {
      int n = n0 + wn + j * 16 + l16;
#pragma unroll
      for (int r = 0; r < 4; r++)
        out[((size_t)b * CO + cobase + r) * NPB + n] = acc[i][j][r];
    }
  }
}

// ---------------------------------------------------------------------------
// in-place instance norm (+leaky), NPIX per (b,c)
template <int NPIX>
__global__ __launch_bounds__(256) void k_inorm(float* __restrict__ x) {
  constexpr int E = NPIX / 256;
  float* p = x + (size_t)blockIdx.x * NPIX;
  const int t = threadIdx.x;
  float v[E];
  float sum = 0.f, sq = 0.f;
#pragma unroll
  for (int i = 0; i < E; i++) {
    v[i] = p[i * 256 + t];
    sum += v[i];
    sq += v[i] * v[i];
  }
#pragma unroll
  for (int o = 32; o > 0; o >>= 1) {
    sum += __shfl_down(sum, o, 64);
    sq += __shfl_down(sq, o, 64);
  }
  __shared__ float red[8];
  int wid = t >> 6;
  if ((t & 63) == 0) {
    red[wid] = sum;
    red[4 + wid] = sq;
  }
  __syncthreads();
  float S = red[0] + red[1] + red[2] + red[3];
  float SQ = red[4] + red[5] + red[6] + red[7];
  float m = S * (1.0f / NPIX);
  float var = SQ * (1.0f / NPIX) - m * m;
  float inv = rsqrtf(var + 1e-5f);
#pragma unroll
  for (int i = 0; i < E; i++) p[i * 256 + t] = LRELU((v[i] - m) * inv);
}

// ---------------------------------------------------------------------------
// fused q/k/v 1x1 projections. grid (B, 40): y<4 q, y<8 k, else v (chunked bf16)
__global__ __launch_bounds__(256) void k_proj_qkv(
    const float* __restrict__ xin, const float* __restrict__ wq,
    const float* __restrict__ bq, const float* __restrict__ wk,
    const float* __restrict__ bk, const float* __restrict__ wv,
    const float* __restrict__ bv, const int* __restrict__ sidx,
    float* __restrict__ q, float* __restrict__ kout, unsigned short* __restrict__ vpk) {
  __shared__ float xsh[32 * 256];
  __shared__ float wsh[16 * 32];
  const int t = threadIdx.x;
  const int b = blockIdx.x;
  const int y = blockIdx.y;
  const int s = sidx[b];
  const int cg = t >> 6, ng = t & 63;
  const float* w;
  const float* bias;
  int co0, nn0, CO;
  if (y < 8) {
    w = (y < 4) ? wq : wk;
    bias = (y < 4) ? bq : bk;
    co0 = 0;
    nn0 = (y & 3) * 256;
    CO = 16;
  } else {
    w = wv;
    bias = bv;
    co0 = ((y - 8) >> 2) * 16;
    nn0 = ((y - 8) & 3) * 256;
    CO = 128;
  }
  const float* xb = xin + (size_t)b * 128 * 1024;
  float4 acc4[4];
#pragma unroll
  for (int c = 0; c < 4; c++) {
    float bb = bias[s * CO + co0 + cg * 4 + c];
    acc4[c] = make_float4(bb, bb, bb, bb);
  }
  for (int cc = 0; cc < 4; cc++) {
#pragma unroll
    for (int k = 0; k < 8; k++) {
      int id = t + (k << 8);
      int ci = id >> 6, nf = id & 63;
      ((float4*)xsh)[id] = ((const float4*)(xb + (cc * 32 + ci) * 1024 + nn0))[nf];
    }
    if (t < 128)
      ((float4*)wsh)[t] =
          ((const float4*)(w + ((size_t)(s * CO + co0 + (t >> 3))) * 128 + cc * 32))[t & 7];
    __syncthreads();
#pragma unroll
    for (int ci4 = 0; ci4 < 8; ci4++) {
      float4 wvv[4], xv[4];
#pragma unroll
      for (int c = 0; c < 4; c++) wvv[c] = ((const float4*)wsh)[(cg * 4 + c) * 8 + ci4];
#pragma unroll
      for (int i = 0; i < 4; i++) xv[i] = ((const float4*)xsh)[(ci4 * 4 + i) * 64 + ng];
#pragma unroll
      for (int c = 0; c < 4; c++)
#pragma unroll
        for (int i = 0; i < 4; i++) {
          float wvc = i == 0 ? wvv[c].x : i == 1 ? wvv[c].y : i == 2 ? wvv[c].z : wvv[c].w;
          acc4[c].x += wvc * xv[i].x;
          acc4[c].y += wvc * xv[i].y;
          acc4[c].z += wvc * xv[i].z;
          acc4[c].w += wvc * xv[i].w;
        }
    }
    __syncthreads();
  }
  if (y < 8) {
    float* out = (y < 4) ? q : kout;
#pragma unroll
    for (int c = 0; c < 4; c++)
      ((float4*)(out + ((size_t)b * 16 + cg * 4 + c) * 1024 + nn0))[ng] = acc4[c];
  } else {
    int n = nn0 + ng * 4;
#pragma unroll
    for (int c = 0; c < 4; c++) {
      int co = co0 + cg * 4 + c;
      bf16x4 u;
      u[0] = f2bf(acc4[c].x);
      u[1] = f2bf(acc4[c].y);
      u[2] = f2bf(acc4[c].z);
      u[3] = f2bf(acc4[c].w);
      *(bf16x4*)(vpk + (((size_t)b * 32 + (n >> 5)) * 128 + co) * 32 + (n & 31)) = u;
    }
  }
}

// ---------------------------------------------------------------------------
// fused self-attention (proven round-9 version)
__global__ __launch_bounds__(256) void k_attn(
    const float* __restrict__ q, const float* __restrict__ k,
    const unsigned short* __restrict__ vpk, const float* __restrict__ x1,
    const float* __restrict__ gamma, const int* __restrict__ sidx,
    unsigned short* __restrict__ ybf) {
  __shared__ __align__(16) short Psh[16 * 1032];
  __shared__ float qsh[256];
  __shared__ float redm[64], reds[64];
  const int t = threadIdx.x;
  const int b = blockIdx.x >> 6;
  const int n0 = (blockIdx.x & 63) << 4;
  const int lane = t & 63, wv = t >> 6;
  const int quad = lane >> 4, l16 = lane & 15;
  const float* qb = q + (size_t)b * 16 * 1024;
  const float* kb = k + (size_t)b * 16 * 1024;
  const float* xb = x1 + (size_t)b * 128 * 1024;

  qsh[t] = qb[((t >> 4) << 10) + n0 + (t & 15)];
  __syncthreads();

  float acc[4][16];
#pragma unroll
  for (int j = 0; j < 4; j++)
#pragma unroll
    for (int nl = 0; nl < 16; nl++) acc[j][nl] = 0.0f;
#pragma unroll
  for (int c = 0; c < 16; c++) {
    float4 kv = *(const float4*)(kb + (c << 10) + 4 * t);
    const float* qr = qsh + c * 16;
#pragma unroll
    for (int j = 0; j < 4; j++) {
      float kk = j == 0 ? kv.x : j == 1 ? kv.y : j == 2 ? kv.z : kv.w;
#pragma unroll
      for (int nl = 0; nl < 16; nl++) acc[j][nl] += kk * qr[nl];
    }
  }
  float lmax[16];
#pragma unroll
  for (int nl = 0; nl < 16; nl++)
    lmax[nl] = fmaxf(fmaxf(acc[0][nl], acc[1][nl]), fmaxf(acc[2][nl], acc[3][nl]));
#pragma unroll
  for (int o = 32; o > 0; o >>= 1)
#pragma unroll
    for (int nl = 0; nl < 16; nl++) lmax[nl] = fmaxf(lmax[nl], __shfl_xor(lmax[nl], o, 64));
  if (lane == 0)
#pragma unroll
    for (int nl = 0; nl < 16; nl++) redm[wv * 16 + nl] = lmax[nl];
  __syncthreads();
#pragma unroll
  for (int nl = 0; nl < 16; nl++)
    lmax[nl] = fmaxf(fmaxf(redm[nl], redm[16 + nl]), fmaxf(redm[32 + nl], redm[48 + nl]));
  float lsum[16];
#pragma unroll
  for (int nl = 0; nl < 16; nl++) lsum[nl] = 0.0f;
#pragma unroll
  for (int j = 0; j < 4; j++)
#pragma unroll
    for (int nl = 0; nl < 16; nl++) {
      float e = __expf(acc[j][nl] - lmax[nl]);
      acc[j][nl] = e;
      lsum[nl] += e;
    }
#pragma unroll
  for (int o = 32; o > 0; o >>= 1)
#pragma unroll
    for (int nl = 0; nl < 16; nl++) lsum[nl] += __shfl_xor(lsum[nl], o, 64);
  if (lane == 0)
#pragma unroll
    for (int nl = 0; nl < 16; nl++) reds[wv * 16 + nl] = lsum[nl];
#pragma unroll
  for (int nl = 0; nl < 16; nl++) {
    bf16x4 pv;
    pv[0] = f2bf(acc[0][nl]);
    pv[1] = f2bf(acc[1][nl]);
    pv[2] = f2bf(acc[2][nl]);
    pv[3] = f2bf(acc[3][nl]);
    *(bf16x4*)&Psh[nl * 1032 + 4 * t] = pv;
  }
  __syncthreads();

  const unsigned short* vp =
      vpk + ((size_t)b * 32 * 128 + (size_t)(wv * 32 + l16)) * 32 + quad * 8;
  const short* prow = Psh + l16 * 1032 + quad * 8;
  f32x4 dacc[2];
  dacc[0] = (f32x4){0.f, 0.f, 0.f, 0.f};
  dacc[1] = (f32x4){0.f, 0.f, 0.f, 0.f};
#pragma unroll 8
  for (int mt = 0; mt < 32; mt++) {
    bf16x8 af0 = *(const bf16x8*)(vp + mt * 4096);
    bf16x8 af1 = *(const bf16x8*)(vp + 512 + mt * 4096);
    bf16x8 bfr = *(const bf16x8*)(prow + mt * 32);
    dacc[0] = __builtin_amdgcn_mfma_f32_16x16x32_bf16(af0, bfr, dacc[0], 0, 0, 0);
    dacc[1] = __builtin_amdgcn_mfma_f32_16x16x32_bf16(af1, bfr, dacc[1], 0, 0, 0);
  }
  __syncthreads();

  float* Osh = (float*)Psh;
  short* Osh2 = Psh + 4352;
#pragma unroll
  for (int i = 0; i < 2; i++) {
    int cob = wv * 32 + i * 16 + quad * 4;
#pragma unroll
    for (int r = 0; r < 4; r++) Osh[(cob + r) * 17 + l16] = dacc[i][r];
  }
  __syncthreads();
  float g = gamma[sidx[b]];
  {
    int co = t >> 1, j0 = (t & 1) * 8;
    const float* xr = xb + (co << 10) + n0 + j0;
    float4 xv0 = *(const float4*)xr;
    float4 xv1 = *(const float4*)(xr + 4);
    float xs[8] = {xv0.x, xv0.y, xv0.z, xv0.w, xv1.x, xv1.y, xv1.z, xv1.w};
#pragma unroll
    for (int j = 0; j < 8; j++) {
      int nl = j0 + j;
      float rs = 1.0f / (reds[nl] + reds[16 + nl] + reds[32 + nl] + reds[48 + nl]);
      Osh2[nl * 136 + co] = f2bf(g * Osh[co * 17 + nl] * rs + xs[j]);
    }
  }
  __syncthreads();
  {
    int nl = t >> 4, cg = t & 15;
    bf16x8 u = *(const bf16x8*)&Osh2[nl * 136 + cg * 8];
    *(bf16x8*)(ybf + ((size_t)b * 1024 + n0 + nl) * 128 + cg * 8) = u;
  }
}

// ---------------------------------------------------------------------------
// conv2 + instance-norm fused, 512 threads: waves 0-3 do kc 0..31 (n-range
// wvn*64), waves 4-7 do kc 32..63; partials combined via LDS, then fused
// per-co mean/var + normalize + lrelu store. grid (B,16); 2048 waves total.
__global__ __launch_bounds__(512) void k_conv2f(
    const unsigned short* __restrict__ ybf, const unsigned short* __restrict__ wr,
    const int* __restrict__ sidx, float* __restrict__ x2) {
  constexpr int CI = 128, CO = 256;
  __shared__ float pacc[4 * 64 * 16];  // 16 KB partial exchange
  __shared__ float rsum[4][16], rsq[4][16];
  const int t = threadIdx.x;
  const int b = blockIdx.x;
  const int co0 = blockIdx.y * 16;
  const int s = sidx[b];
  const int lane = t & 63, wv = t >> 6;
  const int wvn = wv & 3, wh = wv >> 2;
  const int quad = lane >> 4, l16 = lane & 15;

  const unsigned short* aptr = wr + (size_t)(s * CO + co0 + l16) * (CI * 16) + quad * 8;
  const unsigned short* xb = ybf + (size_t)b * 1024 * CI;
  int ihb[4], iwb[4];
#pragma unroll
  for (int j = 0; j < 4; j++) {
    int p = wvn * 64 + j * 16 + l16;
    int oh = p >> 4, ow = p & 15;
    ihb[j] = 2 * oh - 1;
    iwb[j] = 2 * ow - 1;
  }
  f32x4 acc[4];
#pragma unroll
  for (int j = 0; j < 4; j++) acc[j] = (f32x4){0.f, 0.f, 0.f, 0.f};

  const int kc0 = wh * 32;
#pragma unroll 4
  for (int kk = 0; kk < 32; kk++) {
    int kc = kc0 + kk;
    int tap = kc >> 2;
    int cio = (kc & 3) * 32 + quad * 8;
    int kh = tap >> 2, kw = tap & 3;
    bf16x8 af = *(const bf16x8*)(aptr + kc * 32);
#pragma unroll
    for (int j = 0; j < 4; j++) {
      int ih = ihb[j] + kh, iw = iwb[j] + kw;
      bf16x8 bv = {0, 0, 0, 0, 0, 0, 0, 0};
      if ((unsigned)ih < 32u && (unsigned)iw < 32u)
        bv = *(const bf16x8*)(xb + ((size_t)(ih * 32 + iw)) * CI + cio);
      acc[j] = __builtin_amdgcn_mfma_f32_16x16x32_bf16(af, bv, acc[j], 0, 0, 0);
    }
  }
  // combine K-halves: waves wh=1 publish, wh=0 accumulate
  if (wh == 1) {
    float* pp = pacc + (wvn * 64 + lane) * 16;
#pragma unroll
    for (int j = 0; j < 4; j++)
#pragma unroll
      for (int r = 0; r < 4; r++) pp[j * 4 + r] = acc[j][r];
  }
  __syncthreads();
  if (wh == 0) {
    const float* pp = pacc + (wvn * 64 + lane) * 16;
#pragma unroll
    for (int j = 0; j < 4; j++)
#pragma unroll
      for (int r = 0; r < 4; r++) acc[j][r] += pp[j * 4 + r];
    // per-co partial sums over this wave's 64 n (C/D: col(n)=l16, row=quad*4+r)
#pragma unroll
    for (int r = 0; r < 4; r++) {
      float sv = 0.f, qv = 0.f;
#pragma unroll
      for (int j = 0; j < 4; j++) {
        float v = acc[j][r];
        sv += v;
        qv += v * v;
      }
#pragma unroll
      for (int o = 8; o > 0; o >>= 1) {
        sv += __shfl_xor(sv, o, 64);
        qv += __shfl_xor(qv, o, 64);
      }
      if (l16 == 0) {
        rsum[wvn][quad * 4 + r] = sv;
        rsq[wvn][quad * 4 + r] = qv;
      }
    }
  }
  __syncthreads();
  if (wh == 0) {
#pragma unroll
    for (int r = 0; r < 4; r++) {
      int cof = quad * 4 + r;
      float S = rsum[0][cof] + rsum[1][cof] + rsum[2][cof] + rsum[3][cof];
      float SQ = rsq[0][cof] + rsq[1][cof] + rsq[2][cof] + rsq[3][cof];
      float m = S * (1.0f / 256.0f);
      float var = SQ * (1.0f / 256.0f) - m * m;
      float inv = rsqrtf(var + 1e-5f);
      float* orow = x2 + ((size_t)b * CO + co0 + cof) * 256;
#pragma unroll
      for (int j = 0; j < 4; j++) {
        float v = (acc[j][r] - m) * inv;
        orow[wvn * 64 + j * 16 + l16] = LRELU(v);
      }
    }
  }
}

// ---------------------------------------------------------------------------
// head: init out with bias, then partial conv via LDS + atomicAdd (proven r8/9)
__global__ __launch_bounds__(256) void k_head_init(
    const float* __restrict__ bh, const int* __restrict__ sidx, float* __restrict__ out) {
  int i = blockIdx.x * 256 + threadIdx.x;
  if (i < 3600) out[i] = bh[sidx[i / 225]];
}

__global__ __launch_bounds__(256) void k_head_part(
    const float* __restrict__ x2, const float* __restrict__ wh,
    const int* __restrict__ sidx, float* __restrict__ out) {
  __shared__ float Xs[32 * 256];
  __shared__ float Wsh[512];
  const int t = threadIdx.x;
  const int b = blockIdx.x, cc = blockIdx.y;
  const int s = sidx[b];
  const float* xp = x2 + ((size_t)b * 256 + cc * 32) * 256;
#pragma unroll
  for (int i = 0; i < 32; i++) Xs[i * 256 + t] = xp[i * 256 + t];
#pragma unroll
  for (int i = 0; i < 2; i++) {
    int idx = i * 256 + t;
    Wsh[idx] = wh[s * 4096 + cc * 512 + idx];
  }
  __syncthreads();
  if (t < 225) {
    int oh = t / 15, ow = t % 15;
    float acc = 0.0f;
    for (int ci = 0; ci < 32; ci++) {
      const float* xr = Xs + ci * 256;
      const float* wr = Wsh + ci * 16;
#pragma unroll
      for (int kh = 0; kh < 4; kh++) {
        int ih = oh - 1 + kh;
        if ((unsigned)ih >= 16u) continue;
#pragma unroll
        for (int kw = 0; kw < 4; kw++) {
          int iw = ow - 1 + kw;
          if ((unsigned)iw >= 16u) continue;
          acc += wr[kh * 4 + kw] * xr[(ih << 4) + iw];
        }
      }
    }
    atomicAdd(out + b * 225 + t, acc);
  }
}

// ---------------------------------------------------------------------------
extern "C" void kernel_launch(void* const* d_in, const int* in_sizes, int n_in,
                              void* d_out, int out_size, void* d_ws, size_t ws_size,
                              hipStream_t stream) {
  const float* img = (const float*)d_in[0];
  const int* sidx = (const int*)d_in[1];
  const float* w0 = (const float*)d_in[2];
  const float* b0 = (const float*)d_in[3];
  const float* w1 = (const float*)d_in[4];
  const float* w2 = (const float*)d_in[6];
  const float* wq = (const float*)d_in[8];
  const float* bq = (const float*)d_in[9];
  const float* wk = (const float*)d_in[10];
  const float* bk = (const float*)d_in[11];
  const float* wv = (const float*)d_in[12];
  const float* bv = (const float*)d_in[13];
  const float* gamma = (const float*)d_in[14];
  const float* wh = (const float*)d_in[15];
  const float* bh = (const float*)d_in[16];
  float* out = (float*)d_out;

  float* ws = (float*)d_ws;
  unsigned short* x0t = (unsigned short*)(ws);            // [0,2M) floats span
  float* x1 = ws + 2097152;                               // [2M,4M)
  float* q = ws + 4194304;                                // [4M,4.25M)
  float* k = ws + 4456448;                                // [4.25M,4.5M)
  unsigned short* vpk = (unsigned short*)(ws + 4718592);  // [4.5M,5.5M)
  unsigned short* ybf = (unsigned short*)(ws + 5767168);  // [5.5M,6.5M)
  float* x2 = ws + 6815744;                               // [6.5M,7.5M)
  unsigned short* wr1 = (unsigned short*)(ws + 8388608);  // [8M,8.25M)
  unsigned short* wr2 = (unsigned short*)(ws + 8650752);  // [8.25M,9.25M)

  const int B = 16;

  k_repack_all<<<10240, 256, 0, stream>>>(w1, wr1, w2, wr2);
  k_conv0<<<dim3(B, 256), 256, 0, stream>>>(img, w0, b0, sidx, x0t);
  k_conv1<<<dim3(B, 32), 256, 0, stream>>>(x0t, wr1, sidx, x1);
  k_inorm<1024><<<B * 128, 256, 0, stream>>>(x1);
  k_proj_qkv<<<dim3(B, 40), 256, 0, stream>>>(x1, wq, bq, wk, bk, wv, bv, sidx, q, k, vpk);
  k_attn<<<B * 64, 256, 0, stream>>>(q, k, vpk, x1, gamma, sidx, ybf);
  k_conv2f<<<dim3(B, 16), 512, 0, stream>>>(ybf, wr2, sidx, x2);
  k_head_init<<<15, 256, 0, stream>>>(bh, sidx, out);
  k_head_part<<<dim3(B, 8), 256, 0, stream>>>(x2, wh, sidx, out);
}